// Round 2
// baseline (243.192 us; speedup 1.0000x reference)
//
#include <hip/hip_runtime.h>
#include <math.h>

#define B_  2
#define S_  2048
#define D_  1024
#define H_  16
#define HD_ 64
#define M_  (B_*S_)

typedef __attribute__((ext_vector_type(8)))  short s8v;   // 8 bf16 (4 VGPRs)
typedef __attribute__((ext_vector_type(4)))  int   i4v;
typedef __attribute__((ext_vector_type(4)))  float f4v;
typedef __attribute__((ext_vector_type(16))) float f16x;  // 32x32 C/D
#define MFMA16(a,b,c) __builtin_amdgcn_mfma_f32_16x16x32_bf16(a,b,c,0,0,0)
#define MFMA32(a,b,c) __builtin_amdgcn_mfma_f32_32x32x16_bf16(a,b,c,0,0,0)

typedef __attribute__((address_space(1))) const unsigned int uint_ga;
typedef __attribute__((address_space(3))) unsigned int       uint_ls;

__device__ __forceinline__ unsigned short f2bf(float x) {   // RNE
    unsigned u = __float_as_uint(x);
    u += 0x7FFF + ((u >> 16) & 1);
    return (unsigned short)(u >> 16);
}
// async global->LDS, 16B per lane; LDS dest = wave-uniform base + lane*16
__device__ __forceinline__ void gld16(const unsigned short* g, short* l) {
    __builtin_amdgcn_global_load_lds((uint_ga*)g, (uint_ls*)l, 16, 0, 0);
}

#define SCALE2 0.1803368801111204f   /* 0.125 * log2(e) */
#define MXF2   16.0f

#define KHALF  (S_ / 2)               /* 1024 keys per wave-group */
#define NT_    (KHALF / 64)           /* 16 iterations per group */

// ---------------------------------------------------------------------------
// fp32 -> bf16 for X and weights + RoPE table (fused). grid = (4096, 6)
// y==5: cos/sin table, packed float2, layout [j=0..31][s]
// ---------------------------------------------------------------------------
__global__ __launch_bounds__(256) void cvt_bf16_kernel(
    const float* __restrict__ X,  const float* __restrict__ Wq,
    const float* __restrict__ Wk, const float* __restrict__ Wv,
    const float* __restrict__ Wo,
    unsigned short* __restrict__ Xb,  unsigned short* __restrict__ Wqb,
    unsigned short* __restrict__ Wkb, unsigned short* __restrict__ Wvb,
    unsigned short* __restrict__ Wob, float2* __restrict__ cst)
{
    int y = blockIdx.y;
    if (y == 5) {
        int i = blockIdx.x * 256 + threadIdx.x;
        if (i < S_ * 32) {
            int j = i >> 11, s = i & 2047;
            double inv = pow(10000.0, -(double)j / 32.0);
            double ang = (double)s * inv;
            cst[i] = make_float2((float)cos(ang), (float)sin(ang));
        }
        return;
    }
    const float* src = (y==0)?X:(y==1)?Wq:(y==2)?Wk:(y==3)?Wv:Wo;
    unsigned short* dst = (y==0)?Xb:(y==1)?Wqb:(y==2)?Wkb:(y==3)?Wvb:Wob;
    int n = (y==0) ? (M_*D_) : (D_*D_);
    int i = (blockIdx.x*256 + threadIdx.x)*4;
    if (i >= n) return;
    float4 v = *(const float4*)&src[i];
    ushort4 o;
    o.x = f2bf(v.x); o.y = f2bf(v.y); o.z = f2bf(v.z); o.w = f2bf(v.w);
    *(ushort4*)&dst[i] = o;
}

// ---------------------------------------------------------------------------
// m97-style GEMM core: 128x128 tile of C = A . B^T (both row-major, K=D_
// contiguous). 256 thr = 4 waves; wave (wm,wn) owns a 64x64 quadrant,
// 4x4 MFMA16 accs. Staging: global_load_lds dwordx4, XOR chunk swizzle.
// ---------------------------------------------------------------------------
__device__ __forceinline__ void mfma_128x128(
    const unsigned short* __restrict__ Amat, const unsigned short* __restrict__ Bmat,
    int m0, int n0, short* As, short* Bs, f4v acc[4][4])
{
    int tid = threadIdx.x;
    int l = tid & 63, w = tid >> 6;
    int wm = w >> 1, wn = w & 1;
    int lm = l & 15, qd = l >> 4;
    int lm7 = lm & 7;

    f4v z = {0.f, 0.f, 0.f, 0.f};
#pragma unroll
    for (int mt = 0; mt < 4; mt++)
#pragma unroll
        for (int nt = 0; nt < 4; nt++) acc[mt][nt] = z;

    int rl = l >> 3;              // 0..7 row-in-group
    int kc = (l & 7) ^ rl;        // swizzled logical chunk to fetch
    const unsigned short* aG = Amat + (size_t)(m0 + w*32 + rl) * D_ + kc*8;
    const unsigned short* bG = Bmat + (size_t)(n0 + w*32 + rl) * D_ + kc*8;
    short* aL = As + (w*32)*64;
    short* bL = Bs + (w*32)*64;

#pragma unroll 1
    for (int k0 = 0; k0 < D_; k0 += 64) {
        __syncthreads();
#pragma unroll
        for (int j = 0; j < 4; j++) {
            gld16(aG + k0 + (size_t)j*8*D_, aL + j*8*64);
            gld16(bG + k0 + (size_t)j*8*D_, bL + j*8*64);
        }
        __syncthreads();
#pragma unroll
        for (int half = 0; half < 2; half++) {
            int pc = (half*4 + qd) ^ lm7;
            s8v afr[4], bfr[4];
#pragma unroll
            for (int x = 0; x < 4; x++) {
                afr[x] = *(const s8v*)(As + ((wm*64 + x*16 + lm)*8 + pc)*8);
                bfr[x] = *(const s8v*)(Bs + ((wn*64 + x*16 + lm)*8 + pc)*8);
            }
#pragma unroll
            for (int mt = 0; mt < 4; mt++)
#pragma unroll
                for (int nt = 0; nt < 4; nt++)
                    acc[mt][nt] = MFMA16(afr[mt], bfr[nt], acc[mt][nt]);
        }
    }
}

// ---------------------------------------------------------------------------
// K1: QKV projection + RoPE, all in registers. grid = (32, 24).
// Q is written PRE-SCALED by SCALE2 (folds softmax scale into the GEMM).
// ---------------------------------------------------------------------------
__global__ __launch_bounds__(256, 2) void qkv_mfma_kernel(
    const unsigned short* __restrict__ Xb,
    const unsigned short* __restrict__ Wqb, const unsigned short* __restrict__ Wkb,
    const unsigned short* __restrict__ Wvb, const float2* __restrict__ cst,
    unsigned short* __restrict__ Q, unsigned short* __restrict__ K,
    unsigned short* __restrict__ Vt)
{
    __shared__ __align__(16) short As[8192], Bs[8192];
    int bx = blockIdx.x, by = blockIdx.y;
    int proj = by >> 3, f8 = by & 7;
    int l = threadIdx.x & 63, w = threadIdx.x >> 6;
    int wm = w >> 1, wn = w & 1, lm = l & 15, qd = l >> 4;

    f4v acc[4][4];
    if (proj < 2) {
        const unsigned short* Wm = proj ? Wkb : Wqb;
        mfma_128x128(Wm, Xb, f8*128, bx*128, As, Bs, acc);

        int b  = (bx*128) >> 11;
        int sb = ((bx*128) & 2047) + wn*64;
        int bh = b*H_ + f8*2 + wm;
        unsigned short* dst = proj ? K : Q;
        float post = proj ? 1.0f : SCALE2;
#pragma unroll
        for (int mt = 0; mt < 4; mt++) {
            float sgn = (mt < 2) ? -1.f : 1.f;
#pragma unroll
            for (int nt = 0; nt < 4; nt++) {
                int s = sb + nt*16 + lm;
                unsigned short ov[4];
#pragma unroll
                for (int r = 0; r < 4; r++) {
                    int d = mt*16 + qd*4 + r;
                    float2 cs = cst[(d & 31)*S_ + s];
                    float v = acc[mt][nt][r];
                    float p = acc[mt^2][nt][r];
                    ov[r] = f2bf((v*cs.x + sgn*p*cs.y) * post);
                }
                ushort4 ou; ou.x=ov[0]; ou.y=ov[1]; ou.z=ov[2]; ou.w=ov[3];
                *(ushort4*)&dst[((size_t)bh*S_ + s)*HD_ + mt*16 + qd*4] = ou;
            }
        }
    } else {
        mfma_128x128(Xb, Wvb, bx*128, f8*128, As, Bs, acc);

        int b  = (bx*128) >> 11;
        int sb = ((bx*128) & 2047) + wm*64;
        int bh = b*H_ + f8*2 + wn;
#pragma unroll
        for (int mt = 0; mt < 4; mt++)
#pragma unroll
            for (int nt = 0; nt < 4; nt++) {
                int dim = nt*16 + lm;
                int s   = sb + mt*16 + qd*4;
                ushort4 ou;
                ou.x = f2bf(acc[mt][nt][0]);
                ou.y = f2bf(acc[mt][nt][1]);
                ou.z = f2bf(acc[mt][nt][2]);
                ou.w = f2bf(acc[mt][nt][3]);
                *(ushort4*)&Vt[((size_t)bh*HD_ + dim)*S_ + s] = ou;
            }
    }
}

// ---------------------------------------------------------------------------
// K2: flash attention, key-split ACROSS WAVE-GROUPS of one 512-thread block.
// grid = (S_/128, B_*H_) = 512 blocks; 8 waves/block -> 16 waves/CU
// (4 waves/SIMD). Wave-group g (4 waves) sweeps keys [g*1024, g*1024+1024)
// for the block's 128 queries; fixed-max softmax makes partials linear, so
// the epilogue merges group 1 into group 0 through LDS (no HBM partials).
// Per group: register-prefetch LDS double-buffer, ONE barrier per iteration.
// LDS: K dbuf 16K x2 + V dbuf 16K x2 + msk 8K = 72 KB (2 blocks/CU).
// ---------------------------------------------------------------------------
__global__ __launch_bounds__(512, 4) void flash_mfma_kernel(
    const unsigned short* __restrict__ Q, const unsigned short* __restrict__ K,
    const unsigned short* __restrict__ Vt, const int* __restrict__ mask,
    unsigned short* __restrict__ AO)
{
    __shared__ __align__(16) short Ksh[2][2][4096];   // [grp][buf][64x64]
    __shared__ __align__(16) short Vsh[2][2][4096];
    __shared__ __align__(16) float msk[S_];

    int bh = blockIdx.y;
    int b = bh >> 4, h = bh & 15;
    int tid = threadIdx.x;
    int l = tid & 63, w = tid >> 6;        // w 0..7
    int grp = w >> 2, wl = w & 3;          // wave-group, wave-in-group
    int k_base = grp * KHALF;
    int lq = l & 31, hf = l >> 5;
    int q0 = blockIdx.x * 128 + wl * 32;

    {   // mask -> LDS as additive bias (-16 live / -3e38 masked), all 2048 keys
        int i0 = tid * 4;
        const int* mp = mask + b * S_ + i0;
#pragma unroll
        for (int jj = 0; jj < 4; jj++)
            msk[i0 + jj] = mp[jj] ? -MXF2 : -3.0e38f;
    }

    const unsigned short* Qr = Q + ((size_t)bh * S_ + q0 + lq) * HD_ + hf * 8;
    s8v qf[4];
#pragma unroll
    for (int dc = 0; dc < 4; dc++) qf[dc] = *(const s8v*)(Qr + dc * 16);

    f16x zz = {0.f};
    f16x oacc[2]; oacc[0] = zz; oacc[1] = zz;
    f16x lacc = zz;
    s8v ones;
#pragma unroll
    for (int j = 0; j < 8; j++) ones[j] = (short)0x3F80;   // bf16 1.0

    const unsigned short* Kb = K  + (size_t)bh * S_ * HD_;
    const unsigned short* Vb = Vt + (size_t)bh * HD_ * S_;

    int fb0 = 2*wl, fb1 = 2*wl + 1;
    const unsigned short* kS0 = Kb + (size_t)(k_base + (fb0>>2)*32 + lq) * HD_ + (fb0&3)*16 + hf*8;
    const unsigned short* kS1 = Kb + (size_t)(k_base + (fb1>>2)*32 + lq) * HD_ + (fb1&3)*16 + hf*8;
    const unsigned short* vS0 = Vb + (size_t)((fb0>>2)*32 + lq) * S_  + k_base + (fb0&3)*16 + hf*8;
    const unsigned short* vS1 = Vb + (size_t)((fb1>>2)*32 + lq) * S_  + k_base + (fb1&3)*16 + hf*8;

    s8v kr0 = *(const s8v*)(kS0);
    s8v kr1 = *(const s8v*)(kS1);
    s8v vr0 = *(const s8v*)(vS0);
    s8v vr1 = *(const s8v*)(vS1);

#pragma unroll 1
    for (int t = 0; t < NT_; t++) {          // 16 iterations per group
        int buf = t & 1;
        *(s8v*)(&Ksh[grp][buf][fb0*512 + l*8]) = kr0;
        *(s8v*)(&Ksh[grp][buf][fb1*512 + l*8]) = kr1;
        *(s8v*)(&Vsh[grp][buf][fb0*512 + l*8]) = vr0;
        *(s8v*)(&Vsh[grp][buf][fb1*512 + l*8]) = vr1;
        __syncthreads();
        if (t < NT_ - 1) {                   // prefetch next tile into regs
            int koff = (t + 1) * 64;
            kr0 = *(const s8v*)(kS0 + (size_t)koff * HD_);
            kr1 = *(const s8v*)(kS1 + (size_t)koff * HD_);
            vr0 = *(const s8v*)(vS0 + koff);
            vr1 = *(const s8v*)(vS1 + koff);
        }

        // ---- Sc^T = K.Q^T with mask as C-init ----
        int mb = k_base + t * 64;
        f16x sa0, sa1;
#pragma unroll
        for (int g = 0; g < 4; g++) {
            f4v m0 = *(const f4v*)&msk[mb + g*8 + hf*4];
            f4v m1 = *(const f4v*)&msk[mb + 32 + g*8 + hf*4];
#pragma unroll
            for (int i = 0; i < 4; i++) { sa0[g*4+i] = m0[i]; sa1[g*4+i] = m1[i]; }
        }
#pragma unroll
        for (int dc = 0; dc < 4; dc++) {
            s8v kf0 = *(const s8v*)(&Ksh[grp][buf][(0*4+dc)*512 + l*8]);
            sa0 = MFMA32(kf0, qf[dc], sa0);
        }
#pragma unroll
        for (int dc = 0; dc < 4; dc++) {
            s8v kf1 = *(const s8v*)(&Ksh[grp][buf][(1*4+dc)*512 + l*8]);
            sa1 = MFMA32(kf1, qf[dc], sa1);
        }

        // ---- p = exp2(sa), chain-free ----
        float p[32];
#pragma unroll
        for (int r = 0; r < 16; r++) p[r]      = exp2f(sa0[r]);
#pragma unroll
        for (int r = 0; r < 16; r++) p[16 + r] = exp2f(sa1[r]);

        int pk[16];
#pragma unroll
        for (int m = 0; m < 16; m++)
            pk[m] = __builtin_amdgcn_perm(__float_as_uint(p[2*m+1]),
                                          __float_as_uint(p[2*m]), 0x07060302);

        // ---- P^T B-frags + PV + li-by-MFMA ----
#pragma unroll
        for (int kcc = 0; kcc < 4; kcc++) {
            int a = 4*kcc;
            int x01 = hf ? pk[a]   : pk[a+2];
            int x23 = hf ? pk[a+1] : pk[a+3];
            int y01 = __shfl_xor(x01, 32);
            int y23 = __shfl_xor(x23, 32);
            i4v fr;
            fr.x = hf ? y01 : pk[a];
            fr.y = hf ? y23 : pk[a+1];
            fr.z = hf ? pk[a+2] : y01;
            fr.w = hf ? pk[a+3] : y23;
            s8v pf = __builtin_bit_cast(s8v, fr);
#pragma unroll
            for (int dt = 0; dt < 2; dt++) {
                s8v vf = *(const s8v*)(&Vsh[grp][buf][(dt*4+kcc)*512 + l*8]);
                oacc[dt] = MFMA32(vf, pf, oacc[dt]);
            }
            lacc = MFMA32(ones, pf, lacc);
        }
    }

    // ---- cross-group combine through LDS (reuse K/V buffers) ----
    __syncthreads();                          // all compute reads of LDS done
    float* Osh = (float*)&Ksh[0][0][0];       // 32 KB: [128 q][64 d] fp32
    float* Lsh = (float*)&Vsh[0][0][0];       // 128 floats
    int qloc = wl*32 + lq;
    int sw = (qloc & 15) << 2;                // XOR swizzle, keeps 16B align
    if (grp == 1) {
#pragma unroll
        for (int dt = 0; dt < 2; dt++)
#pragma unroll
            for (int g = 0; g < 4; g++) {
                int d0 = dt*32 + g*8 + hf*4;
                f4v o;
                o.x = oacc[dt][g*4 + 0];
                o.y = oacc[dt][g*4 + 1];
                o.z = oacc[dt][g*4 + 2];
                o.w = oacc[dt][g*4 + 3];
                *(f4v*)&Osh[qloc*64 + (d0 ^ sw)] = o;
            }
        if (hf == 0) Lsh[qloc] = lacc[0];
    }
    __syncthreads();
    if (grp == 0) {
        float invl = 1.0f / (lacc[0] + Lsh[qloc]);
        int qtok = blockIdx.x * 128 + qloc;
        unsigned short* Or = AO + ((size_t)(b * S_ + qtok)) * D_ + h * HD_;
#pragma unroll
        for (int dt = 0; dt < 2; dt++)
#pragma unroll
            for (int g = 0; g < 4; g++) {
                int d0 = dt*32 + g*8 + hf*4;
                f4v o1 = *(const f4v*)&Osh[qloc*64 + (d0 ^ sw)];
                ushort4 o;
                o.x = f2bf((oacc[dt][g*4 + 0] + o1.x) * invl);
                o.y = f2bf((oacc[dt][g*4 + 1] + o1.y) * invl);
                o.z = f2bf((oacc[dt][g*4 + 2] + o1.z) * invl);
                o.w = f2bf((oacc[dt][g*4 + 3] + o1.w) * invl);
                *(ushort4*)&Or[d0] = o;
            }
    }
}

// ---------------------------------------------------------------------------
// K3: output projection as C[e][token] = Wo . AO^T; float4 register stores.
// ---------------------------------------------------------------------------
__global__ __launch_bounds__(256, 2) void outproj_mfma_kernel(
    const unsigned short* __restrict__ AO, const unsigned short* __restrict__ Wob,
    float* __restrict__ out)
{
    __shared__ __align__(16) short As[8192], Bs[8192];
    int bx = blockIdx.x, by = blockIdx.y;
    int l = threadIdx.x & 63, w = threadIdx.x >> 6;
    int wm = w >> 1, wn = w & 1, lm = l & 15, qd = l >> 4;

    f4v acc[4][4];
    mfma_128x128(Wob, AO, by*128, bx*128, As, Bs, acc);

#pragma unroll
    for (int mt = 0; mt < 4; mt++)
#pragma unroll
        for (int nt = 0; nt < 4; nt++) {
            int tok = bx*128 + wn*64 + nt*16 + lm;
            int e   = by*128 + wm*64 + mt*16 + qd*4;
            *(f4v*)&out[(size_t)tok*D_ + e] = acc[mt][nt];
        }
}

// ---------------------------------------------------------------------------
// Workspace (u16 units): Xb 4M | W*b 1M x4 | Qb 4M | Kb 4M | Vtb 4M | AOb 4M
// | cst (float2) 64K  ~= 48.5 MB
// ---------------------------------------------------------------------------
extern "C" void kernel_launch(void* const* d_in, const int* in_sizes, int n_in,
                              void* d_out, int out_size, void* d_ws, size_t ws_size,
                              hipStream_t stream)
{
    const float* X    = (const float*)d_in[0];
    const int*   mask = (const int*)  d_in[1];
    const float* Wq   = (const float*)d_in[2];
    const float* Wk   = (const float*)d_in[3];
    const float* Wv   = (const float*)d_in[4];
    const float* Wo   = (const float*)d_in[5];
    float* out = (float*)d_out;

    unsigned short* ws = (unsigned short*)d_ws;
    unsigned short* Xb  = ws;
    unsigned short* Wqb = Xb  + (size_t)M_ * D_;
    unsigned short* Wkb = Wqb + (size_t)D_ * D_;
    unsigned short* Wvb = Wkb + (size_t)D_ * D_;
    unsigned short* Wob = Wvb + (size_t)D_ * D_;
    unsigned short* Qb  = Wob + (size_t)D_ * D_;
    unsigned short* Kb  = Qb  + (size_t)M_ * D_;
    unsigned short* Vtb = Kb  + (size_t)M_ * D_;
    unsigned short* AOb = Vtb + (size_t)M_ * D_;
    float2* cst = (float2*)(AOb + (size_t)M_ * D_);

    cvt_bf16_kernel<<<dim3(4096, 6), 256, 0, stream>>>(
        X, Wq, Wk, Wv, Wo, Xb, Wqb, Wkb, Wvb, Wob, cst);
    qkv_mfma_kernel<<<dim3(32, 24), 256, 0, stream>>>(
        Xb, Wqb, Wkb, Wvb, cst, Qb, Kb, Vtb);
    flash_mfma_kernel<<<dim3(S_ / 128, B_ * H_), 512, 0, stream>>>(
        Qb, Kb, Vtb, mask, AOb);
    outproj_mfma_kernel<<<dim3(32, 8), 256, 0, stream>>>(AOb, Wob, out);
}

// Round 3
// 211.953 us; speedup vs baseline: 1.1474x; 1.1474x over previous
//
#include <hip/hip_runtime.h>
#include <math.h>

#define B_  2
#define S_  2048
#define D_  1024
#define H_  16
#define HD_ 64
#define M_  (B_*S_)

typedef __attribute__((ext_vector_type(8)))  short s8v;   // 8 bf16 (4 VGPRs)
typedef __attribute__((ext_vector_type(4)))  int   i4v;
typedef __attribute__((ext_vector_type(4)))  float f4v;
typedef __attribute__((ext_vector_type(16))) float f16x;  // 32x32 C/D
#define MFMA16(a,b,c) __builtin_amdgcn_mfma_f32_16x16x32_bf16(a,b,c,0,0,0)
#define MFMA32(a,b,c) __builtin_amdgcn_mfma_f32_32x32x16_bf16(a,b,c,0,0,0)

typedef __attribute__((address_space(1))) const unsigned int uint_ga;
typedef __attribute__((address_space(3))) unsigned int       uint_ls;

__device__ __forceinline__ unsigned short f2bf(float x) {   // RNE
    unsigned u = __float_as_uint(x);
    u += 0x7FFF + ((u >> 16) & 1);
    return (unsigned short)(u >> 16);
}
// async global->LDS, 16B per lane; LDS dest = wave-uniform base + lane*16
__device__ __forceinline__ void gld16(const unsigned short* g, short* l) {
    __builtin_amdgcn_global_load_lds((uint_ga*)g, (uint_ls*)l, 16, 0, 0);
}

#define SCALE2 0.1803368801111204f   /* 0.125 * log2(e) */
#define MXF2   16.0f

#define KHALF  (S_ / 2)               /* 1024 keys per wave-group */
#define NT_    (KHALF / 64)           /* 16 iterations per group */

// ---------------------------------------------------------------------------
// fp32 -> bf16 for X and weights + RoPE table (fused). grid = (4096, 6)
// y==5: cos/sin table, packed float2, layout [j=0..31][s]
// ---------------------------------------------------------------------------
__global__ __launch_bounds__(256) void cvt_bf16_kernel(
    const float* __restrict__ X,  const float* __restrict__ Wq,
    const float* __restrict__ Wk, const float* __restrict__ Wv,
    const float* __restrict__ Wo,
    unsigned short* __restrict__ Xb,  unsigned short* __restrict__ Wqb,
    unsigned short* __restrict__ Wkb, unsigned short* __restrict__ Wvb,
    unsigned short* __restrict__ Wob, float2* __restrict__ cst)
{
    int y = blockIdx.y;
    if (y == 5) {
        int i = blockIdx.x * 256 + threadIdx.x;
        if (i < S_ * 32) {
            int j = i >> 11, s = i & 2047;
            double inv = pow(10000.0, -(double)j / 32.0);
            double ang = (double)s * inv;
            cst[i] = make_float2((float)cos(ang), (float)sin(ang));
        }
        return;
    }
    const float* src = (y==0)?X:(y==1)?Wq:(y==2)?Wk:(y==3)?Wv:Wo;
    unsigned short* dst = (y==0)?Xb:(y==1)?Wqb:(y==2)?Wkb:(y==3)?Wvb:Wob;
    int n = (y==0) ? (M_*D_) : (D_*D_);
    int i = (blockIdx.x*256 + threadIdx.x)*4;
    if (i >= n) return;
    float4 v = *(const float4*)&src[i];
    ushort4 o;
    o.x = f2bf(v.x); o.y = f2bf(v.y); o.z = f2bf(v.z); o.w = f2bf(v.w);
    *(ushort4*)&dst[i] = o;
}

// ---------------------------------------------------------------------------
// m97-style GEMM core: 128x128 tile of C = A . B^T (both row-major, K=D_
// contiguous). 256 thr = 4 waves; wave (wm,wn) owns a 64x64 quadrant,
// 4x4 MFMA16 accs. Staging: global_load_lds dwordx4, XOR chunk swizzle.
// ---------------------------------------------------------------------------
__device__ __forceinline__ void mfma_128x128(
    const unsigned short* __restrict__ Amat, const unsigned short* __restrict__ Bmat,
    int m0, int n0, short* As, short* Bs, f4v acc[4][4])
{
    int tid = threadIdx.x;
    int l = tid & 63, w = tid >> 6;
    int wm = w >> 1, wn = w & 1;
    int lm = l & 15, qd = l >> 4;
    int lm7 = lm & 7;

    f4v z = {0.f, 0.f, 0.f, 0.f};
#pragma unroll
    for (int mt = 0; mt < 4; mt++)
#pragma unroll
        for (int nt = 0; nt < 4; nt++) acc[mt][nt] = z;

    int rl = l >> 3;              // 0..7 row-in-group
    int kc = (l & 7) ^ rl;        // swizzled logical chunk to fetch
    const unsigned short* aG = Amat + (size_t)(m0 + w*32 + rl) * D_ + kc*8;
    const unsigned short* bG = Bmat + (size_t)(n0 + w*32 + rl) * D_ + kc*8;
    short* aL = As + (w*32)*64;
    short* bL = Bs + (w*32)*64;

#pragma unroll 1
    for (int k0 = 0; k0 < D_; k0 += 64) {
        __syncthreads();
#pragma unroll
        for (int j = 0; j < 4; j++) {
            gld16(aG + k0 + (size_t)j*8*D_, aL + j*8*64);
            gld16(bG + k0 + (size_t)j*8*D_, bL + j*8*64);
        }
        __syncthreads();
#pragma unroll
        for (int half = 0; half < 2; half++) {
            int pc = (half*4 + qd) ^ lm7;
            s8v afr[4], bfr[4];
#pragma unroll
            for (int x = 0; x < 4; x++) {
                afr[x] = *(const s8v*)(As + ((wm*64 + x*16 + lm)*8 + pc)*8);
                bfr[x] = *(const s8v*)(Bs + ((wn*64 + x*16 + lm)*8 + pc)*8);
            }
#pragma unroll
            for (int mt = 0; mt < 4; mt++)
#pragma unroll
                for (int nt = 0; nt < 4; nt++)
                    acc[mt][nt] = MFMA16(afr[mt], bfr[nt], acc[mt][nt]);
        }
    }
}

// ---------------------------------------------------------------------------
// K1: QKV projection + RoPE, all in registers. grid = (32, 24).
// Q is written PRE-SCALED by SCALE2 (folds softmax scale into the GEMM).
// ---------------------------------------------------------------------------
__global__ __launch_bounds__(256, 2) void qkv_mfma_kernel(
    const unsigned short* __restrict__ Xb,
    const unsigned short* __restrict__ Wqb, const unsigned short* __restrict__ Wkb,
    const unsigned short* __restrict__ Wvb, const float2* __restrict__ cst,
    unsigned short* __restrict__ Q, unsigned short* __restrict__ K,
    unsigned short* __restrict__ Vt)
{
    __shared__ __align__(16) short As[8192], Bs[8192];
    int bx = blockIdx.x, by = blockIdx.y;
    int proj = by >> 3, f8 = by & 7;
    int l = threadIdx.x & 63, w = threadIdx.x >> 6;
    int wm = w >> 1, wn = w & 1, lm = l & 15, qd = l >> 4;

    f4v acc[4][4];
    if (proj < 2) {
        const unsigned short* Wm = proj ? Wkb : Wqb;
        mfma_128x128(Wm, Xb, f8*128, bx*128, As, Bs, acc);

        int b  = (bx*128) >> 11;
        int sb = ((bx*128) & 2047) + wn*64;
        int bh = b*H_ + f8*2 + wm;
        unsigned short* dst = proj ? K : Q;
        float post = proj ? 1.0f : SCALE2;
#pragma unroll
        for (int mt = 0; mt < 4; mt++) {
            float sgn = (mt < 2) ? -1.f : 1.f;
#pragma unroll
            for (int nt = 0; nt < 4; nt++) {
                int s = sb + nt*16 + lm;
                unsigned short ov[4];
#pragma unroll
                for (int r = 0; r < 4; r++) {
                    int d = mt*16 + qd*4 + r;
                    float2 cs = cst[(d & 31)*S_ + s];
                    float v = acc[mt][nt][r];
                    float p = acc[mt^2][nt][r];
                    ov[r] = f2bf((v*cs.x + sgn*p*cs.y) * post);
                }
                ushort4 ou; ou.x=ov[0]; ou.y=ov[1]; ou.z=ov[2]; ou.w=ov[3];
                *(ushort4*)&dst[((size_t)bh*S_ + s)*HD_ + mt*16 + qd*4] = ou;
            }
        }
    } else {
        mfma_128x128(Xb, Wvb, bx*128, f8*128, As, Bs, acc);

        int b  = (bx*128) >> 11;
        int sb = ((bx*128) & 2047) + wm*64;
        int bh = b*H_ + f8*2 + wn;
#pragma unroll
        for (int mt = 0; mt < 4; mt++)
#pragma unroll
            for (int nt = 0; nt < 4; nt++) {
                int dim = nt*16 + lm;
                int s   = sb + mt*16 + qd*4;
                ushort4 ou;
                ou.x = f2bf(acc[mt][nt][0]);
                ou.y = f2bf(acc[mt][nt][1]);
                ou.z = f2bf(acc[mt][nt][2]);
                ou.w = f2bf(acc[mt][nt][3]);
                *(ushort4*)&Vt[((size_t)bh*HD_ + dim)*S_ + s] = ou;
            }
    }
}

// ---------------------------------------------------------------------------
// K2: flash attention, key-split across wave-groups of one 512-thread block.
// grid = (S_/128, B_*H_) = 512 blocks; 8 waves/block, 2 blocks/CU ->
// 4 waves/SIMD (launch_bounds cap = 128 regs/thread, unified VGPR+AGPR).
// Register-pressure diet vs round 2 (which spilled ~198 MB to scratch):
//  - K/V staged by global_load_lds (no prefetch regs, no explicit ds_write)
//  - 32-key halves processed sequentially (one sa f16x live at a time)
//  - l by VALU tree-sum (frees 16-AGPR lacc + ones frag, -4 MFMA/iter)
//  - P packed with v_cvt_pk_bf16_f32 (RNE, 8 instr/half)
// LDS: K dbuf 16K x2 + V dbuf 16K x2 + msk 8K = 72 KB (2 blocks/CU).
// ---------------------------------------------------------------------------
__global__ __launch_bounds__(512, 4) void flash_mfma_kernel(
    const unsigned short* __restrict__ Q, const unsigned short* __restrict__ K,
    const unsigned short* __restrict__ Vt, const int* __restrict__ mask,
    unsigned short* __restrict__ AO)
{
    __shared__ __align__(16) short Ksh[2][2][4096];   // [grp][buf][64x64]
    __shared__ __align__(16) short Vsh[2][2][4096];
    __shared__ __align__(16) float msk[S_];

    int bh = blockIdx.y;
    int b = bh >> 4, h = bh & 15;
    int tid = threadIdx.x;
    int l = tid & 63, w = tid >> 6;        // w 0..7
    int grp = w >> 2, wl = w & 3;          // wave-group, wave-in-group
    int k_base = grp * KHALF;
    int lq = l & 31, hf = l >> 5;
    int q0 = blockIdx.x * 128 + wl * 32;

    {   // mask -> LDS as additive bias (-16 live / -3e38 masked), all 2048 keys
        int i0 = tid * 4;
        const int* mp = mask + b * S_ + i0;
#pragma unroll
        for (int jj = 0; jj < 4; jj++)
            msk[i0 + jj] = mp[jj] ? -MXF2 : -3.0e38f;
    }

    const unsigned short* Qr = Q + ((size_t)bh * S_ + q0 + lq) * HD_ + hf * 8;
    s8v qf[4];
#pragma unroll
    for (int dc = 0; dc < 4; dc++) qf[dc] = *(const s8v*)(Qr + dc * 16);

    f16x zz = {0.f};
    f16x oacc[2]; oacc[0] = zz; oacc[1] = zz;
    float lsum = 0.f;

    const unsigned short* Kb = K  + (size_t)bh * S_ * HD_;
    const unsigned short* Vb = Vt + (size_t)bh * HD_ * S_;

    int fb0 = 2*wl, fb1 = 2*wl + 1;
    // per-lane global sources; lane l lands at LDS base + l*16B (gld16 rule)
    const unsigned short* kP0 = Kb + (size_t)(k_base + (fb0>>2)*32 + lq) * HD_ + (fb0&3)*16 + hf*8;
    const unsigned short* kP1 = Kb + (size_t)(k_base + (fb1>>2)*32 + lq) * HD_ + (fb1&3)*16 + hf*8;
    const unsigned short* vP0 = Vb + (size_t)((fb0>>2)*32 + lq) * S_  + k_base + (fb0&3)*16 + hf*8;
    const unsigned short* vP1 = Vb + (size_t)((fb1>>2)*32 + lq) * S_  + k_base + (fb1&3)*16 + hf*8;

    // prologue: issue tile 0 into buf 0
    gld16(kP0, &Ksh[grp][0][fb0*512]);
    gld16(kP1, &Ksh[grp][0][fb1*512]);
    gld16(vP0, &Vsh[grp][0][fb0*512]);
    gld16(vP1, &Vsh[grp][0][fb1*512]);

#pragma unroll 1
    for (int t = 0; t < NT_; t++) {          // 16 iterations per group
        int buf = t & 1;
        __syncthreads();                     // drains gld16s -> buf ready
        if (t < NT_ - 1) {                   // issue next tile into buf^1
            int koff = (t + 1) * 64;
            gld16(kP0 + (size_t)koff * HD_, &Ksh[grp][buf^1][fb0*512]);
            gld16(kP1 + (size_t)koff * HD_, &Ksh[grp][buf^1][fb1*512]);
            gld16(vP0 + koff,               &Vsh[grp][buf^1][fb0*512]);
            gld16(vP1 + koff,               &Vsh[grp][buf^1][fb1*512]);
        }

        int mb = k_base + t * 64;
#pragma unroll
        for (int half = 0; half < 2; half++) {
            // ---- Sc^T = K.Q^T (32 keys x 32 queries) with mask C-init ----
            f16x sa;
#pragma unroll
            for (int g = 0; g < 4; g++) {
                f4v m0 = *(const f4v*)&msk[mb + half*32 + g*8 + hf*4];
#pragma unroll
                for (int i = 0; i < 4; i++) sa[g*4+i] = m0[i];
            }
#pragma unroll
            for (int dc = 0; dc < 4; dc++) {
                s8v kf = *(const s8v*)(&Ksh[grp][buf][(half*4+dc)*512 + l*8]);
                sa = MFMA32(kf, qf[dc], sa);
            }

            // ---- p = exp2(sa); lane-local denominator tree-sum ----
            float ph[16];
#pragma unroll
            for (int r = 0; r < 16; r++) ph[r] = exp2f(sa[r]);
            lsum += (((ph[0]+ph[1])+(ph[2]+ph[3])) + ((ph[4]+ph[5])+(ph[6]+ph[7])))
                  + (((ph[8]+ph[9])+(ph[10]+ph[11])) + ((ph[12]+ph[13])+(ph[14]+ph[15])));

            // ---- pack to bf16 pairs (RNE) ----
            int pkh[8];
#pragma unroll
            for (int m = 0; m < 8; m++) {
                int r;
                asm("v_cvt_pk_bf16_f32 %0, %1, %2"
                    : "=v"(r) : "v"(ph[2*m]), "v"(ph[2*m+1]));
                pkh[m] = r;
            }

            // ---- P^T B-frags + PV ----
#pragma unroll
            for (int kc2 = 0; kc2 < 2; kc2++) {
                int kcc = half*2 + kc2;
                int a = 4*kc2;
                int x01 = hf ? pkh[a]   : pkh[a+2];
                int x23 = hf ? pkh[a+1] : pkh[a+3];
                int y01 = __shfl_xor(x01, 32);
                int y23 = __shfl_xor(x23, 32);
                i4v fr;
                fr.x = hf ? y01 : pkh[a];
                fr.y = hf ? y23 : pkh[a+1];
                fr.z = hf ? pkh[a+2] : y01;
                fr.w = hf ? pkh[a+3] : y23;
                s8v pf = __builtin_bit_cast(s8v, fr);
#pragma unroll
                for (int dt = 0; dt < 2; dt++) {
                    s8v vf = *(const s8v*)(&Vsh[grp][buf][(dt*4+kcc)*512 + l*8]);
                    oacc[dt] = MFMA32(vf, pf, oacc[dt]);
                }
            }
        }
    }

    // pair lane (hf^1) holds the complementary keys' sum
    lsum += __shfl_xor(lsum, 32);

    // ---- cross-group combine through LDS (reuse K/V buffers) ----
    __syncthreads();                          // all compute reads of LDS done
    float* Osh = (float*)&Ksh[0][0][0];       // 32 KB: [128 q][64 d] fp32
    float* Lsh = (float*)&Vsh[0][0][0];       // 128 floats
    int qloc = wl*32 + lq;
    int sw = (qloc & 15) << 2;                // XOR swizzle, keeps 16B align
    if (grp == 1) {
#pragma unroll
        for (int dt = 0; dt < 2; dt++)
#pragma unroll
            for (int g = 0; g < 4; g++) {
                int d0 = dt*32 + g*8 + hf*4;
                f4v o;
                o.x = oacc[dt][g*4 + 0];
                o.y = oacc[dt][g*4 + 1];
                o.z = oacc[dt][g*4 + 2];
                o.w = oacc[dt][g*4 + 3];
                *(f4v*)&Osh[qloc*64 + (d0 ^ sw)] = o;
            }
        if (hf == 0) Lsh[qloc] = lsum;
    }
    __syncthreads();
    if (grp == 0) {
        float invl = 1.0f / (lsum + Lsh[qloc]);
        int qtok = blockIdx.x * 128 + qloc;
        unsigned short* Or = AO + ((size_t)(b * S_ + qtok)) * D_ + h * HD_;
#pragma unroll
        for (int dt = 0; dt < 2; dt++)
#pragma unroll
            for (int g = 0; g < 4; g++) {
                int d0 = dt*32 + g*8 + hf*4;
                f4v o1 = *(const f4v*)&Osh[qloc*64 + (d0 ^ sw)];
                ushort4 o;
                o.x = f2bf((oacc[dt][g*4 + 0] + o1.x) * invl);
                o.y = f2bf((oacc[dt][g*4 + 1] + o1.y) * invl);
                o.z = f2bf((oacc[dt][g*4 + 2] + o1.z) * invl);
                o.w = f2bf((oacc[dt][g*4 + 3] + o1.w) * invl);
                *(ushort4*)&Or[d0] = o;
            }
    }
}

// ---------------------------------------------------------------------------
// K3: output projection as C[e][token] = Wo . AO^T; float4 register stores.
// ---------------------------------------------------------------------------
__global__ __launch_bounds__(256, 2) void outproj_mfma_kernel(
    const unsigned short* __restrict__ AO, const unsigned short* __restrict__ Wob,
    float* __restrict__ out)
{
    __shared__ __align__(16) short As[8192], Bs[8192];
    int bx = blockIdx.x, by = blockIdx.y;
    int l = threadIdx.x & 63, w = threadIdx.x >> 6;
    int wm = w >> 1, wn = w & 1, lm = l & 15, qd = l >> 4;

    f4v acc[4][4];
    mfma_128x128(Wob, AO, by*128, bx*128, As, Bs, acc);

#pragma unroll
    for (int mt = 0; mt < 4; mt++)
#pragma unroll
        for (int nt = 0; nt < 4; nt++) {
            int tok = bx*128 + wn*64 + nt*16 + lm;
            int e   = by*128 + wm*64 + mt*16 + qd*4;
            *(f4v*)&out[(size_t)tok*D_ + e] = acc[mt][nt];
        }
}

// ---------------------------------------------------------------------------
// Workspace (u16 units): Xb 4M | W*b 1M x4 | Qb 4M | Kb 4M | Vtb 4M | AOb 4M
// | cst (float2) 64K  ~= 48.5 MB
// ---------------------------------------------------------------------------
extern "C" void kernel_launch(void* const* d_in, const int* in_sizes, int n_in,
                              void* d_out, int out_size, void* d_ws, size_t ws_size,
                              hipStream_t stream)
{
    const float* X    = (const float*)d_in[0];
    const int*   mask = (const int*)  d_in[1];
    const float* Wq   = (const float*)d_in[2];
    const float* Wk   = (const float*)d_in[3];
    const float* Wv   = (const float*)d_in[4];
    const float* Wo   = (const float*)d_in[5];
    float* out = (float*)d_out;

    unsigned short* ws = (unsigned short*)d_ws;
    unsigned short* Xb  = ws;
    unsigned short* Wqb = Xb  + (size_t)M_ * D_;
    unsigned short* Wkb = Wqb + (size_t)D_ * D_;
    unsigned short* Wvb = Wkb + (size_t)D_ * D_;
    unsigned short* Wob = Wvb + (size_t)D_ * D_;
    unsigned short* Qb  = Wob + (size_t)D_ * D_;
    unsigned short* Kb  = Qb  + (size_t)M_ * D_;
    unsigned short* Vtb = Kb  + (size_t)M_ * D_;
    unsigned short* AOb = Vtb + (size_t)M_ * D_;
    float2* cst = (float2*)(AOb + (size_t)M_ * D_);

    cvt_bf16_kernel<<<dim3(4096, 6), 256, 0, stream>>>(
        X, Wq, Wk, Wv, Wo, Xb, Wqb, Wkb, Wvb, Wob, cst);
    qkv_mfma_kernel<<<dim3(32, 24), 256, 0, stream>>>(
        Xb, Wqb, Wkb, Wvb, cst, Qb, Kb, Vtb);
    flash_mfma_kernel<<<dim3(S_ / 128, B_ * H_), 512, 0, stream>>>(
        Qb, Kb, Vtb, mask, AOb);
    outproj_mfma_kernel<<<dim3(32, 8), 256, 0, stream>>>(AOb, Wob, out);
}

// Round 4
// 180.330 us; speedup vs baseline: 1.3486x; 1.1754x over previous
//
#include <hip/hip_runtime.h>
#include <math.h>

#define B_  2
#define S_  2048
#define D_  1024
#define H_  16
#define HD_ 64
#define M_  (B_*S_)

typedef __attribute__((ext_vector_type(8)))  short s8v;   // 8 bf16 (4 VGPRs)
typedef __attribute__((ext_vector_type(4)))  int   i4v;
typedef __attribute__((ext_vector_type(4)))  float f4v;
typedef __attribute__((ext_vector_type(16))) float f16x;  // 32x32 C/D
typedef __attribute__((ext_vector_type(2)))  unsigned int u2v;
#define MFMA16(a,b,c) __builtin_amdgcn_mfma_f32_16x16x32_bf16(a,b,c,0,0,0)
#define MFMA32(a,b,c) __builtin_amdgcn_mfma_f32_32x32x16_bf16(a,b,c,0,0,0)

typedef __attribute__((address_space(1))) const unsigned int uint_ga;
typedef __attribute__((address_space(3))) unsigned int       uint_ls;

__device__ __forceinline__ unsigned short f2bf(float x) {   // RNE
    unsigned u = __float_as_uint(x);
    u += 0x7FFF + ((u >> 16) & 1);
    return (unsigned short)(u >> 16);
}
// async global->LDS, 16B per lane; LDS dest = wave-uniform base + lane*16
__device__ __forceinline__ void gld16(const unsigned short* g, short* l) {
    __builtin_amdgcn_global_load_lds((uint_ga*)g, (uint_ls*)l, 16, 0, 0);
}

#define SCALE2 0.1803368801111204f   /* 0.125 * log2(e) */
#define MXF2   16.0f

#define KHALF  (S_ / 2)               /* 1024 keys per wave-group */
#define NT_    (KHALF / 64)           /* 16 iterations per group */

// ---------------------------------------------------------------------------
// fp32 -> bf16 for X and weights + RoPE table (fused). grid = (4096, 6)
// y==5: cos/sin table, packed float2, layout [j=0..31][s]
// ---------------------------------------------------------------------------
__global__ __launch_bounds__(256) void cvt_bf16_kernel(
    const float* __restrict__ X,  const float* __restrict__ Wq,
    const float* __restrict__ Wk, const float* __restrict__ Wv,
    const float* __restrict__ Wo,
    unsigned short* __restrict__ Xb,  unsigned short* __restrict__ Wqb,
    unsigned short* __restrict__ Wkb, unsigned short* __restrict__ Wvb,
    unsigned short* __restrict__ Wob, float2* __restrict__ cst)
{
    int y = blockIdx.y;
    if (y == 5) {
        int i = blockIdx.x * 256 + threadIdx.x;
        if (i < S_ * 32) {
            int j = i >> 11, s = i & 2047;
            double inv = pow(10000.0, -(double)j / 32.0);
            double ang = (double)s * inv;
            cst[i] = make_float2((float)cos(ang), (float)sin(ang));
        }
        return;
    }
    const float* src = (y==0)?X:(y==1)?Wq:(y==2)?Wk:(y==3)?Wv:Wo;
    unsigned short* dst = (y==0)?Xb:(y==1)?Wqb:(y==2)?Wkb:(y==3)?Wvb:Wob;
    int n = (y==0) ? (M_*D_) : (D_*D_);
    int i = (blockIdx.x*256 + threadIdx.x)*4;
    if (i >= n) return;
    float4 v = *(const float4*)&src[i];
    ushort4 o;
    o.x = f2bf(v.x); o.y = f2bf(v.y); o.z = f2bf(v.z); o.w = f2bf(v.w);
    *(ushort4*)&dst[i] = o;
}

// ---------------------------------------------------------------------------
// m97-style GEMM core: 128x128 tile of C = A . B^T (both row-major, K
// contiguous), over K range [klo, klo+kcnt). gtid = 256-thread group-local
// tid; 4 waves; wave (wm,wn) owns a 64x64 quadrant, 4x4 MFMA16 accs.
// Staging: global_load_lds dwordx4, XOR chunk swizzle.
// NOTE: contains 2 __syncthreads per k-step -> all groups in a block must
// execute the same number of k-steps for barrier alignment.
// ---------------------------------------------------------------------------
__device__ __forceinline__ void mfma_128x128_span(
    const unsigned short* __restrict__ Amat, const unsigned short* __restrict__ Bmat,
    int m0, int n0, int klo, int kcnt, short* As, short* Bs, f4v acc[4][4], int gtid)
{
    int l = gtid & 63, w = gtid >> 6;
    int wm = w >> 1, wn = w & 1;
    int lm = l & 15, qd = l >> 4;
    int lm7 = lm & 7;

    f4v z = {0.f, 0.f, 0.f, 0.f};
#pragma unroll
    for (int mt = 0; mt < 4; mt++)
#pragma unroll
        for (int nt = 0; nt < 4; nt++) acc[mt][nt] = z;

    int rl = l >> 3;              // 0..7 row-in-group
    int kc = (l & 7) ^ rl;        // swizzled logical chunk to fetch
    const unsigned short* aG = Amat + (size_t)(m0 + w*32 + rl) * D_ + kc*8;
    const unsigned short* bG = Bmat + (size_t)(n0 + w*32 + rl) * D_ + kc*8;
    short* aL = As + (w*32)*64;
    short* bL = Bs + (w*32)*64;

#pragma unroll 1
    for (int k0 = klo; k0 < klo + kcnt; k0 += 64) {
        __syncthreads();
#pragma unroll
        for (int j = 0; j < 4; j++) {
            gld16(aG + k0 + (size_t)j*8*D_, aL + j*8*64);
            gld16(bG + k0 + (size_t)j*8*D_, bL + j*8*64);
        }
        __syncthreads();
#pragma unroll
        for (int half = 0; half < 2; half++) {
            int pc = (half*4 + qd) ^ lm7;
            s8v afr[4], bfr[4];
#pragma unroll
            for (int x = 0; x < 4; x++) {
                afr[x] = *(const s8v*)(As + ((wm*64 + x*16 + lm)*8 + pc)*8);
                bfr[x] = *(const s8v*)(Bs + ((wn*64 + x*16 + lm)*8 + pc)*8);
            }
#pragma unroll
            for (int mt = 0; mt < 4; mt++)
#pragma unroll
                for (int nt = 0; nt < 4; nt++)
                    acc[mt][nt] = MFMA16(afr[mt], bfr[nt], acc[mt][nt]);
        }
    }
}

__device__ __forceinline__ void mfma_128x128(
    const unsigned short* __restrict__ Amat, const unsigned short* __restrict__ Bmat,
    int m0, int n0, short* As, short* Bs, f4v acc[4][4])
{
    mfma_128x128_span(Amat, Bmat, m0, n0, 0, D_, As, Bs, acc, threadIdx.x);
}

// ---------------------------------------------------------------------------
// K1: QKV projection + RoPE, all in registers. grid = (32, 24).
// Q is written PRE-SCALED by SCALE2 (folds softmax scale into the GEMM).
// ---------------------------------------------------------------------------
__global__ __launch_bounds__(256, 2) void qkv_mfma_kernel(
    const unsigned short* __restrict__ Xb,
    const unsigned short* __restrict__ Wqb, const unsigned short* __restrict__ Wkb,
    const unsigned short* __restrict__ Wvb, const float2* __restrict__ cst,
    unsigned short* __restrict__ Q, unsigned short* __restrict__ K,
    unsigned short* __restrict__ Vt)
{
    __shared__ __align__(16) short As[8192], Bs[8192];
    int bx = blockIdx.x, by = blockIdx.y;
    int proj = by >> 3, f8 = by & 7;
    int l = threadIdx.x & 63, w = threadIdx.x >> 6;
    int wm = w >> 1, wn = w & 1, lm = l & 15, qd = l >> 4;

    f4v acc[4][4];
    if (proj < 2) {
        const unsigned short* Wm = proj ? Wkb : Wqb;
        mfma_128x128(Wm, Xb, f8*128, bx*128, As, Bs, acc);

        int b  = (bx*128) >> 11;
        int sb = ((bx*128) & 2047) + wn*64;
        int bh = b*H_ + f8*2 + wm;
        unsigned short* dst = proj ? K : Q;
        float post = proj ? 1.0f : SCALE2;
#pragma unroll
        for (int mt = 0; mt < 4; mt++) {
            float sgn = (mt < 2) ? -1.f : 1.f;
#pragma unroll
            for (int nt = 0; nt < 4; nt++) {
                int s = sb + nt*16 + lm;
                unsigned short ov[4];
#pragma unroll
                for (int r = 0; r < 4; r++) {
                    int d = mt*16 + qd*4 + r;
                    float2 cs = cst[(d & 31)*S_ + s];
                    float v = acc[mt][nt][r];
                    float p = acc[mt^2][nt][r];
                    ov[r] = f2bf((v*cs.x + sgn*p*cs.y) * post);
                }
                ushort4 ou; ou.x=ov[0]; ou.y=ov[1]; ou.z=ov[2]; ou.w=ov[3];
                *(ushort4*)&dst[((size_t)bh*S_ + s)*HD_ + mt*16 + qd*4] = ou;
            }
        }
    } else {
        mfma_128x128(Xb, Wvb, bx*128, f8*128, As, Bs, acc);

        int b  = (bx*128) >> 11;
        int sb = ((bx*128) & 2047) + wm*64;
        int bh = b*H_ + f8*2 + wn;
#pragma unroll
        for (int mt = 0; mt < 4; mt++)
#pragma unroll
            for (int nt = 0; nt < 4; nt++) {
                int dim = nt*16 + lm;
                int s   = sb + mt*16 + qd*4;
                ushort4 ou;
                ou.x = f2bf(acc[mt][nt][0]);
                ou.y = f2bf(acc[mt][nt][1]);
                ou.z = f2bf(acc[mt][nt][2]);
                ou.w = f2bf(acc[mt][nt][3]);
                *(ushort4*)&Vt[((size_t)bh*HD_ + dim)*S_ + s] = ou;
            }
    }
}

// ---------------------------------------------------------------------------
// K2: flash attention, key-split across wave-groups of one 512-thread block.
// grid = (S_/128, B_*H_) = 512 blocks; 8 waves/block, 2 blocks/CU.
// XCD-aware remap: hardware round-robins linear block id over 8 XCDs, so
// wk = (flat&7)*64 + (flat>>3) gives each XCD 4 bh x 16 q-tiles ->
// K/V working set 2 MB/XCD, L2-resident (lower load latency at the
// per-iteration barrier drain).
// P-exchange via v_permlane32_swap (VALU) instead of ds_bpermute;
// exp2 via __builtin_amdgcn_exp2f (bare v_exp_f32); setprio around MFMA.
// LDS: K dbuf 16K x2 + V dbuf 16K x2 + msk 8K = 72 KB (2 blocks/CU).
// ---------------------------------------------------------------------------
__global__ __launch_bounds__(512, 4) void flash_mfma_kernel(
    const unsigned short* __restrict__ Q, const unsigned short* __restrict__ K,
    const unsigned short* __restrict__ Vt, const int* __restrict__ mask,
    unsigned short* __restrict__ AO)
{
    __shared__ __align__(16) short Ksh[2][2][4096];   // [grp][buf][64x64]
    __shared__ __align__(16) short Vsh[2][2][4096];
    __shared__ __align__(16) float msk[S_];

    int flat = blockIdx.y * (S_/128) + blockIdx.x;    // 0..511
    int wk   = (flat & 7) * 64 + (flat >> 3);         // XCD-contiguous remap
    int bh   = wk >> 4;
    int qx   = wk & 15;
    int b = bh >> 4, h = bh & 15;
    int tid = threadIdx.x;
    int l = tid & 63, w = tid >> 6;        // w 0..7
    int grp = w >> 2, wl = w & 3;          // wave-group, wave-in-group
    int k_base = grp * KHALF;
    int lq = l & 31, hf = l >> 5;
    int q0 = qx * 128 + wl * 32;

    {   // mask -> LDS as additive bias (-16 live / -3e38 masked), all 2048 keys
        int i0 = tid * 4;
        const int* mp = mask + b * S_ + i0;
#pragma unroll
        for (int jj = 0; jj < 4; jj++)
            msk[i0 + jj] = mp[jj] ? -MXF2 : -3.0e38f;
    }

    const unsigned short* Qr = Q + ((size_t)bh * S_ + q0 + lq) * HD_ + hf * 8;
    s8v qf[4];
#pragma unroll
    for (int dc = 0; dc < 4; dc++) qf[dc] = *(const s8v*)(Qr + dc * 16);

    f16x zz = {0.f};
    f16x oacc[2]; oacc[0] = zz; oacc[1] = zz;
    float lsum = 0.f;

    const unsigned short* Kb = K  + (size_t)bh * S_ * HD_;
    const unsigned short* Vb = Vt + (size_t)bh * HD_ * S_;

    int fb0 = 2*wl, fb1 = 2*wl + 1;
    // per-lane global sources; lane l lands at LDS base + l*16B (gld16 rule)
    const unsigned short* kP0 = Kb + (size_t)(k_base + (fb0>>2)*32 + lq) * HD_ + (fb0&3)*16 + hf*8;
    const unsigned short* kP1 = Kb + (size_t)(k_base + (fb1>>2)*32 + lq) * HD_ + (fb1&3)*16 + hf*8;
    const unsigned short* vP0 = Vb + (size_t)((fb0>>2)*32 + lq) * S_  + k_base + (fb0&3)*16 + hf*8;
    const unsigned short* vP1 = Vb + (size_t)((fb1>>2)*32 + lq) * S_  + k_base + (fb1&3)*16 + hf*8;

    // prologue: issue tile 0 into buf 0
    gld16(kP0, &Ksh[grp][0][fb0*512]);
    gld16(kP1, &Ksh[grp][0][fb1*512]);
    gld16(vP0, &Vsh[grp][0][fb0*512]);
    gld16(vP1, &Vsh[grp][0][fb1*512]);

#pragma unroll 1
    for (int t = 0; t < NT_; t++) {          // 16 iterations per group
        int buf = t & 1;
        __syncthreads();                     // drains gld16s -> buf ready
        if (t < NT_ - 1) {                   // issue next tile into buf^1
            int koff = (t + 1) * 64;
            gld16(kP0 + (size_t)koff * HD_, &Ksh[grp][buf^1][fb0*512]);
            gld16(kP1 + (size_t)koff * HD_, &Ksh[grp][buf^1][fb1*512]);
            gld16(vP0 + koff,               &Vsh[grp][buf^1][fb0*512]);
            gld16(vP1 + koff,               &Vsh[grp][buf^1][fb1*512]);
        }

        int mb = k_base + t * 64;
#pragma unroll
        for (int half = 0; half < 2; half++) {
            // ---- Sc^T = K.Q^T (32 keys x 32 queries) with mask C-init ----
            f16x sa;
#pragma unroll
            for (int g = 0; g < 4; g++) {
                f4v m0 = *(const f4v*)&msk[mb + half*32 + g*8 + hf*4];
#pragma unroll
                for (int i = 0; i < 4; i++) sa[g*4+i] = m0[i];
            }
            __builtin_amdgcn_s_setprio(1);
#pragma unroll
            for (int dc = 0; dc < 4; dc++) {
                s8v kf = *(const s8v*)(&Ksh[grp][buf][(half*4+dc)*512 + l*8]);
                sa = MFMA32(kf, qf[dc], sa);
            }
            __builtin_amdgcn_s_setprio(0);

            // ---- p = exp2(sa); lane-local denominator tree-sum ----
            float ph[16];
#pragma unroll
            for (int r = 0; r < 16; r++) ph[r] = __builtin_amdgcn_exp2f(sa[r]);
            lsum += (((ph[0]+ph[1])+(ph[2]+ph[3])) + ((ph[4]+ph[5])+(ph[6]+ph[7])))
                  + (((ph[8]+ph[9])+(ph[10]+ph[11])) + ((ph[12]+ph[13])+(ph[14]+ph[15])));

            // ---- pack to bf16 pairs (RNE) ----
            int pkh[8];
#pragma unroll
            for (int m = 0; m < 8; m++) {
                int r;
                asm("v_cvt_pk_bf16_f32 %0, %1, %2"
                    : "=v"(r) : "v"(ph[2*m]), "v"(ph[2*m+1]));
                pkh[m] = r;
            }

            // ---- P^T B-frags via permlane32_swap + PV ----
#pragma unroll
            for (int kc2 = 0; kc2 < 2; kc2++) {
                int kcc = half*2 + kc2;
                int a = 4*kc2;
                // swap D.hi <-> S.lo: D'={D.lo,S.lo}, S'={D.hi,S.hi}
                u2v r02 = __builtin_amdgcn_permlane32_swap(
                    (unsigned)pkh[a],   (unsigned)pkh[a+2], false, false);
                u2v r13 = __builtin_amdgcn_permlane32_swap(
                    (unsigned)pkh[a+1], (unsigned)pkh[a+3], false, false);
                i4v fr;
                fr.x = (int)r02[0];
                fr.y = (int)r13[0];
                fr.z = (int)r02[1];
                fr.w = (int)r13[1];
                s8v pf = __builtin_bit_cast(s8v, fr);
                __builtin_amdgcn_s_setprio(1);
#pragma unroll
                for (int dt = 0; dt < 2; dt++) {
                    s8v vf = *(const s8v*)(&Vsh[grp][buf][(dt*4+kcc)*512 + l*8]);
                    oacc[dt] = MFMA32(vf, pf, oacc[dt]);
                }
                __builtin_amdgcn_s_setprio(0);
            }
        }
    }

    // pair lane (hf^1) holds the complementary keys' sum
    lsum += __shfl_xor(lsum, 32);

    // ---- cross-group combine through LDS (reuse K/V buffers) ----
    __syncthreads();                          // all compute reads of LDS done
    float* Osh = (float*)&Ksh[0][0][0];       // 32 KB: [128 q][64 d] fp32
    float* Lsh = (float*)&Vsh[0][0][0];       // 128 floats
    int qloc = wl*32 + lq;
    int sw = (qloc & 15) << 2;                // XOR swizzle, keeps 16B align
    if (grp == 1) {
#pragma unroll
        for (int dt = 0; dt < 2; dt++)
#pragma unroll
            for (int g = 0; g < 4; g++) {
                int d0 = dt*32 + g*8 + hf*4;
                f4v o;
                o.x = oacc[dt][g*4 + 0];
                o.y = oacc[dt][g*4 + 1];
                o.z = oacc[dt][g*4 + 2];
                o.w = oacc[dt][g*4 + 3];
                *(f4v*)&Osh[qloc*64 + (d0 ^ sw)] = o;
            }
        if (hf == 0) Lsh[qloc] = lsum;
    }
    __syncthreads();
    if (grp == 0) {
        float invl = 1.0f / (lsum + Lsh[qloc]);
        int qtok = qx * 128 + qloc;
        unsigned short* Or = AO + ((size_t)(b * S_ + qtok)) * D_ + h * HD_;
#pragma unroll
        for (int dt = 0; dt < 2; dt++)
#pragma unroll
            for (int g = 0; g < 4; g++) {
                int d0 = dt*32 + g*8 + hf*4;
                f4v o1 = *(const f4v*)&Osh[qloc*64 + (d0 ^ sw)];
                ushort4 o;
                o.x = f2bf((oacc[dt][g*4 + 0] + o1.x) * invl);
                o.y = f2bf((oacc[dt][g*4 + 1] + o1.y) * invl);
                o.z = f2bf((oacc[dt][g*4 + 2] + o1.z) * invl);
                o.w = f2bf((oacc[dt][g*4 + 3] + o1.w) * invl);
                *(ushort4*)&Or[d0] = o;
            }
    }
}

// ---------------------------------------------------------------------------
// K3: output projection as C[e][token] = Wo . AO^T, K-SPLIT across two
// wave-groups of a 512-thread block (was 256 thr = 1 block/CU = 4 waves/CU,
// fully latency-exposed). Group g accumulates over K in [512g, 512g+512);
// partials merged through LDS (XOR-swizzled) then written as float4.
// LDS 64 KB; grid (32,8) = 256 blocks -> 8 waves/CU.
// ---------------------------------------------------------------------------
__global__ __launch_bounds__(512, 2) void outproj_mfma_kernel(
    const unsigned short* __restrict__ AO, const unsigned short* __restrict__ Wob,
    float* __restrict__ out)
{
    __shared__ __align__(16) short SM[2][2][8192];   // [grp][A/B] = 64 KB
    int tid = threadIdx.x;
    int grp = tid >> 8, gtid = tid & 255;
    int bx = blockIdx.x, by = blockIdx.y;
    int l = gtid & 63, w4 = gtid >> 6;
    int wm = w4 >> 1, wn = w4 & 1, lm = l & 15, qd = l >> 4;

    f4v acc[4][4];
    mfma_128x128_span(Wob, AO, by*128, bx*128, grp*512, 512,
                      SM[grp][0], SM[grp][1], acc, gtid);

    __syncthreads();                          // GEMM LDS reads done
    float* Csh = (float*)&SM[0][0][0];        // 64 KB = 128x128 fp32
    if (grp == 1) {
#pragma unroll
        for (int mt = 0; mt < 4; mt++)
#pragma unroll
            for (int nt = 0; nt < 4; nt++) {
                int tokl = wn*64 + nt*16 + lm;
                int el   = wm*64 + mt*16 + qd*4;
                *(f4v*)&Csh[tokl*128 + (el ^ ((tokl & 7) << 2))] = acc[mt][nt];
            }
    }
    __syncthreads();
    if (grp == 0) {
#pragma unroll
        for (int mt = 0; mt < 4; mt++)
#pragma unroll
            for (int nt = 0; nt < 4; nt++) {
                int tokl = wn*64 + nt*16 + lm;
                int el   = wm*64 + mt*16 + qd*4;
                f4v p = *(const f4v*)&Csh[tokl*128 + (el ^ ((tokl & 7) << 2))];
                f4v o = acc[mt][nt] + p;
                int tok = bx*128 + tokl;
                int e   = by*128 + el;
                *(f4v*)&out[(size_t)tok*D_ + e] = o;
            }
    }
}

// ---------------------------------------------------------------------------
// Workspace (u16 units): Xb 4M | W*b 1M x4 | Qb 4M | Kb 4M | Vtb 4M | AOb 4M
// | cst (float2) 64K  ~= 48.5 MB
// ---------------------------------------------------------------------------
extern "C" void kernel_launch(void* const* d_in, const int* in_sizes, int n_in,
                              void* d_out, int out_size, void* d_ws, size_t ws_size,
                              hipStream_t stream)
{
    const float* X    = (const float*)d_in[0];
    const int*   mask = (const int*)  d_in[1];
    const float* Wq   = (const float*)d_in[2];
    const float* Wk   = (const float*)d_in[3];
    const float* Wv   = (const float*)d_in[4];
    const float* Wo   = (const float*)d_in[5];
    float* out = (float*)d_out;

    unsigned short* ws = (unsigned short*)d_ws;
    unsigned short* Xb  = ws;
    unsigned short* Wqb = Xb  + (size_t)M_ * D_;
    unsigned short* Wkb = Wqb + (size_t)D_ * D_;
    unsigned short* Wvb = Wkb + (size_t)D_ * D_;
    unsigned short* Wob = Wvb + (size_t)D_ * D_;
    unsigned short* Qb  = Wob + (size_t)D_ * D_;
    unsigned short* Kb  = Qb  + (size_t)M_ * D_;
    unsigned short* Vtb = Kb  + (size_t)M_ * D_;
    unsigned short* AOb = Vtb + (size_t)M_ * D_;
    float2* cst = (float2*)(AOb + (size_t)M_ * D_);

    cvt_bf16_kernel<<<dim3(4096, 6), 256, 0, stream>>>(
        X, Wq, Wk, Wv, Wo, Xb, Wqb, Wkb, Wvb, Wob, cst);
    qkv_mfma_kernel<<<dim3(32, 24), 256, 0, stream>>>(
        Xb, Wqb, Wkb, Wvb, cst, Qb, Kb, Vtb);
    flash_mfma_kernel<<<dim3(S_ / 128, B_ * H_), 512, 0, stream>>>(
        Qb, Kb, Vtb, mask, AOb);
    outproj_mfma_kernel<<<dim3(32, 8), 512, 0, stream>>>(AOb, Wob, out);
}